// Round 1
// baseline (225.571 us; speedup 1.0000x reference)
//
#include <hip/hip_runtime.h>
#include <math.h>

// FIRE bias: out[h,i,j] = MLP(nd(i,j)) where
//   nd = log((|i-j|+eps)*c + 1 + eps) / log(|c*(max(i,thr)+eps)| + 1 + eps)
//   MLP: relu(nd*w1 + b1) dot w2 + b2   (1 -> 32 -> 12)
//
// Piecewise-linear MLP trick (from prev session) + NEW: all transcendentals
// hoisted into tiny 1-D tables (lr[d] depends only on d=|i-j|, ln/invln only
// on row i). Per-block we fold inv_ln into alpha and ln_i into the sorted
// thresholds, so the main kernel's per-element work is 1 LDS read + 6-step
// branchless search + 12 FMA. Output 192 MiB fp32, nontemporal stores.

#define SDIM 2048
#define WDIM 32
#define HDIM 12
#define NK 33            // intervals = WDIM + 1
#define EPSF 1e-6f
#define LOGB 1.0f

typedef float f32x4 __attribute__((ext_vector_type(4)));

// ws layout (floats):
//   [0..63]        sorted thresholds (nd-space), padded to 64 with +INF
//   [64..64+792)   interleaved (alpha,beta) per (k,h)   2*NK*HDIM = 792
//   [896..2944)    lr[d]   = log((d+eps)*c + 1 + eps),   d in [0,2048)
//   [2944..4992)   ln[i]   = log(|c*(max(i,thr)+eps)| + 1 + eps)
//   [4992..7040)   invln[i] = 1/ln[i]
#define WS_T   0
#define WS_AB  64
#define WS_LR  896
#define WS_LN  2944
#define WS_ILN 4992
#define WS_TOTAL 7040     // 28.2 KB

__global__ __launch_bounds__(512) void fire_precompute(
    const float* __restrict__ w1, const float* __restrict__ b1,
    const float* __restrict__ w2, const float* __restrict__ b2,
    const float* __restrict__ cptr, const float* __restrict__ lmptr,
    const float* __restrict__ ilptr, float* __restrict__ ws)
{
    const int tid = threadIdx.x;

    if (blockIdx.x != 0) {
        // blocks 1..4: tabulate lr / ln / invln (bit-identical math to the
        // previously-inlined expressions)
        const int d = ((int)blockIdx.x - 1) * 512 + tid;   // 0..2047
        const float c = cptr[0];
        ws[WS_LR + d] = logf(fmaf((float)d + EPSF, c, LOGB + EPSF));
        const float thr = fabsf(lmptr[0] * ilptr[0]);
        const float pn  = fmaxf((float)d, thr) + EPSF;
        const float ln  = logf(fabsf(c * pn) + LOGB + EPSF);
        ws[WS_LN  + d] = ln;
        ws[WS_ILN + d] = 1.0f / ln;
        return;
    }

    __shared__ float traw[WDIM], w1s[WDIM], b1s[WDIM];
    __shared__ int rnk[WDIM], neg[WDIM];

    if (tid < WDIM) {
        float a = w1[tid], b = b1[tid];
        w1s[tid] = a; b1s[tid] = b;
        float t; int isneg;
        if (a > 0.f)      { t = -b / a; isneg = 0; }
        else if (a < 0.f) { t = -b / a; isneg = 1; }
        else {
            // w1==0: relu(b1) constant. "always active" (t=-inf) if b1>0,
            // "never active" (t=+inf) otherwise; treat as positive slope.
            t = (b > 0.f) ? -INFINITY : INFINITY; isneg = 0;
        }
        traw[tid] = t; neg[tid] = isneg;
    }
    __syncthreads();

    if (tid < WDIM) {
        // rank via O(W^2) counting sort (ties broken by index)
        float t = traw[tid];
        int r = 0;
        for (int v = 0; v < WDIM; ++v) {
            float tv = traw[v];
            if (tv < t || (tv == t && v < tid)) r++;
        }
        rnk[tid] = r;
        ws[WS_T + r] = t;
    } else if (tid < 64) {
        ws[WS_T + tid] = INFINITY;   // pad for 6-step binary search
    }
    __syncthreads();

    // interval k: t_sorted[k-1] <= nd < t_sorted[k]  (k in [0,32])
    // positive-slope w active iff rank(w) < k; negative-slope iff rank(w) >= k
    if (tid < NK * HDIM) {
        const int k = tid % NK;
        const int h = tid / NK;
        float a = 0.f, bb = 0.f;
        for (int w = 0; w < WDIM; ++w) {
            const bool active = neg[w] ? (rnk[w] >= k) : (rnk[w] < k);
            if (active) {
                float w2v = w2[h * WDIM + w];
                a  += w2v * w1s[w];
                bb += w2v * b1s[w];
            }
        }
        bb += b2[h];
        ws[WS_AB + (k * HDIM + h) * 2 + 0] = a;
        ws[WS_AB + (k * HDIM + h) * 2 + 1] = bb;
    }
}

__global__ __launch_bounds__(512) void fire_main(
    const float* __restrict__ ws, float* __restrict__ out)
{
    __shared__ float sTp[64];                 // thresholds scaled by ln_i
    __shared__ float sAB[2 * NK * HDIM];      // alpha pre-scaled by inv_ln
    __shared__ __align__(16) float sLR[SDIM]; // lr[d] table
    const int tid = threadIdx.x;
    const int i = blockIdx.x;

    // ln_i > 0 always (log(|...|+1+eps) >= log(1+eps) > 0), so scaling the
    // thresholds by ln_i preserves the comparison  lr*inv_ln > t  <=>  lr > t*ln_i.
    // Any ulp-level k-flip lands exactly at a breakpoint of a CONTINUOUS
    // piecewise-linear function -> output change is ulp-level.
    const float ln_i = ws[WS_LN  + i];
    const float ivl  = ws[WS_ILN + i];

    ((f32x4*)sLR)[tid] = ((const f32x4*)(ws + WS_LR))[tid];   // 2048 floats
    if (tid < 64) sTp[tid] = ws[WS_T + tid] * ln_i;           // INF*ln_i = INF ok
    for (int idx = tid; idx < 2 * NK * HDIM; idx += 512) {
        float v = ws[WS_AB + idx];
        if ((idx & 1) == 0) v *= ivl;         // even offsets are alphas
        sAB[idx] = v;
    }
    __syncthreads();

    const int j0 = tid * 4;                   // 512 threads * 4 = one row
    float lrv[4];
    int kk[4];
    #pragma unroll
    for (int e = 0; e < 4; ++e) {
        int j = j0 + e;
        int dd = i - j; if (dd < 0) dd = -dd;
        float x = sLR[dd];
        // branchless lower_bound over 64-padded scaled thresholds -> k in [0,32]
        int k = 0;
        if (x > sTp[k + 31]) k += 32;
        if (x > sTp[k + 15]) k += 16;
        if (x > sTp[k + 7])  k += 8;
        if (x > sTp[k + 3])  k += 4;
        if (x > sTp[k + 1])  k += 2;
        if (x > sTp[k])      k += 1;
        kk[e] = k;
        lrv[e] = x;
    }

    const size_t base = (size_t)i * SDIM + (size_t)j0;
    #pragma unroll
    for (int h = 0; h < HDIM; ++h) {
        f32x4 v;
        #pragma unroll
        for (int e = 0; e < 4; ++e) {
            int idx = (kk[e] * HDIM + h) * 2;
            v[e] = fmaf(sAB[idx], lrv[e], sAB[idx + 1]);
        }
        // write-once output, never re-read: bypass cache churn
        __builtin_nontemporal_store(v, (f32x4*)(out + (size_t)h * SDIM * SDIM + base));
    }
}

extern "C" void kernel_launch(void* const* d_in, const int* in_sizes, int n_in,
                              void* d_out, int out_size, void* d_ws, size_t ws_size,
                              hipStream_t stream)
{
    // inputs: 0:x (unused, shape only), 1:w1[32], 2:b1[32], 3:w2[12,32],
    //         4:b2[12], 5:c, 6:L_multiplier, 7:init_L
    const float* w1 = (const float*)d_in[1];
    const float* b1 = (const float*)d_in[2];
    const float* w2 = (const float*)d_in[3];
    const float* b2 = (const float*)d_in[4];
    const float* c  = (const float*)d_in[5];
    const float* lm = (const float*)d_in[6];
    const float* il = (const float*)d_in[7];
    float* ws  = (float*)d_ws;
    float* out = (float*)d_out;

    fire_precompute<<<5, 512, 0, stream>>>(w1, b1, w2, b2, c, lm, il, ws);
    fire_main<<<SDIM, 512, 0, stream>>>(ws, out);
}